// Round 1
// baseline (236.122 us; speedup 1.0000x reference)
//
#include <hip/hip_runtime.h>

#define N_NODES 20000
#define D 128
#define K 16
#define STEPS 2
#define LAYERS 2
#define E_EDGES 8192

__device__ __forceinline__ float wave_reduce_sum(float v) {
    #pragma unroll
    for (int off = 32; off > 0; off >>= 1)
        v += __shfl_xor(v, off, 64);
    return v;
}

// Kernel A: Wsum[l][d] = sum_f layer_w[l][f][d]; also zero the output scalar.
__global__ void prep_kernel(const float* __restrict__ layer_w,
                            float* __restrict__ wsum,
                            float* __restrict__ out) {
    int t = threadIdx.x;            // 0..255
    int l = t >> 7, d = t & 127;
    float s = 0.f;
    const float* p = layer_w + (size_t)l * D * D + d;
    #pragma unroll 8
    for (int f = 0; f < D; ++f) s += p[(size_t)f * D];
    wsum[l * D + d] = s;
    if (t == 0) out[0] = 0.f;
}

// Kernel B: attention for every node. One wave per node, 2 dims per lane.
__global__ __launch_bounds__(256) void attn_kernel(
    const int* __restrict__ neighbors, const float* __restrict__ emb,
    const float* __restrict__ fc_w, const float* __restrict__ fc_b,
    float* __restrict__ att)
{
    int wave = (int)((blockIdx.x * blockDim.x + threadIdx.x) >> 6);
    int lane = threadIdx.x & 63;
    if (wave >= N_NODES) return;
    const int n = wave;
    const int d0 = lane * 2;

    float2 wn = *(const float2*)(fc_w + d0);        // w_n = fc_w[:D]
    float2 ws = *(const float2*)(fc_w + D + d0);    // w_s = fc_w[D:]
    float2 es = *(const float2*)(emb + (size_t)n * D + d0);
    float self_score = wave_reduce_sum(es.x * ws.x + es.y * ws.y);
    float bias = fc_b[0];

    // out = sum over steps of (attn-agg + K*emb[n])
    float acc0 = (float)(STEPS * K) * es.x;
    float acc1 = (float)(STEPS * K) * es.y;

    for (int s = 0; s < STEPS; ++s) {
        const int* nb = neighbors + ((size_t)s * N_NODES + n) * K;
        float vx[K], vy[K], sc[K];
        #pragma unroll
        for (int k = 0; k < K; ++k) {
            int idx = nb[k];
            float2 v = *(const float2*)(emb + (size_t)idx * D + d0);
            vx[k] = v.x; vy[k] = v.y;
            float s_k = wave_reduce_sum(v.x * wn.x + v.y * wn.y) + self_score + bias;
            sc[k] = (s_k >= 0.f) ? s_k : 0.2f * s_k;   // leaky relu
        }
        // softmax over K (all lanes hold identical scores)
        float m = sc[0];
        #pragma unroll
        for (int k = 1; k < K; ++k) m = fmaxf(m, sc[k]);
        float den = 0.f;
        #pragma unroll
        for (int k = 0; k < K; ++k) { sc[k] = __expf(sc[k] - m); den += sc[k]; }
        float inv = 1.f / den;
        #pragma unroll
        for (int k = 0; k < K; ++k) {
            float a = sc[k] * inv;
            acc0 += a * vx[k];
            acc1 += a * vy[k];
        }
    }
    *(float2*)(att + (size_t)n * D + d0) = make_float2(acc0, acc1);
}

// Kernel C: per-edge loss. One wave per edge, 2 dims per lane.
__global__ __launch_bounds__(256) void edge_kernel(
    const int* __restrict__ edges, const int* __restrict__ labels,
    const float* __restrict__ emb, const float* __restrict__ att,
    const float* __restrict__ wsum, const float* __restrict__ layer_b,
    float* __restrict__ out)
{
    int wave = (int)((blockIdx.x * blockDim.x + threadIdx.x) >> 6);
    int lane = threadIdx.x & 63;
    if (wave >= E_EDGES) return;
    const int e = wave;
    const int lab = labels[e];
    const int s = edges[2 * e], t = edges[2 * e + 1];
    const float* base = (lab == 1) ? att : emb;
    const int d0 = lane * 2;

    float2 xs = *(const float2*)(base + (size_t)s * D + d0);
    float2 xd = *(const float2*)(base + (size_t)t * D + d0);
    float2 w0 = *(const float2*)(wsum + d0);
    float2 w1 = *(const float2*)(wsum + D + d0);
    float2 b0 = *(const float2*)(layer_b + d0);
    float2 b1 = *(const float2*)(layer_b + D + d0);

    float ss0 = fmaxf(xs.x * w0.x + b0.x, 0.f) + fmaxf(xs.x * w1.x + b1.x, 0.f);
    float ss1 = fmaxf(xs.y * w0.y + b0.y, 0.f) + fmaxf(xs.y * w1.y + b1.y, 0.f);
    float dd0 = fmaxf(xd.x * w0.x + b0.x, 0.f) + fmaxf(xd.x * w1.x + b1.x, 0.f);
    float dd1 = fmaxf(xd.y * w0.y + b0.y, 0.f) + fmaxf(xd.y * w1.y + b1.y, 0.f);

    float t0 = ss0 - dd0, t1 = ss1 - dd1;
    float ssq = wave_reduce_sum(t0 * t0 + t1 * t1);
    if (lane == 0) {
        float diff = ssq * (1.0f / (float)D);
        float pred = __expf(-diff);
        float l = (float)lab - pred;
        atomicAdd(out, 0.5f * l * l);
    }
}

extern "C" void kernel_launch(void* const* d_in, const int* in_sizes, int n_in,
                              void* d_out, int out_size, void* d_ws, size_t ws_size,
                              hipStream_t stream) {
    const int*   edges     = (const int*)  d_in[0];
    const int*   labels    = (const int*)  d_in[1];
    const int*   neighbors = (const int*)  d_in[2];
    const float* emb       = (const float*)d_in[3];
    const float* fc_w      = (const float*)d_in[4];
    const float* fc_b      = (const float*)d_in[5];
    const float* layer_w   = (const float*)d_in[6];
    const float* layer_b   = (const float*)d_in[7];
    float* out  = (float*)d_out;
    float* att  = (float*)d_ws;                       // N*D floats = 10.24 MB
    float* wsum = att + (size_t)N_NODES * D;          // LAYERS*D floats

    prep_kernel<<<1, 256, 0, stream>>>(layer_w, wsum, out);

    int attn_blocks = (N_NODES + 3) / 4;              // 4 waves (nodes) / block
    attn_kernel<<<attn_blocks, 256, 0, stream>>>(neighbors, emb, fc_w, fc_b, att);

    int edge_blocks = (E_EDGES + 3) / 4;              // 4 waves (edges) / block
    edge_kernel<<<edge_blocks, 256, 0, stream>>>(edges, labels, emb, att, wsum, layer_b, out);
}

// Round 2
// 155.412 us; speedup vs baseline: 1.5193x; 1.5193x over previous
//
#include <hip/hip_runtime.h>

#define N_NODES 20000
#define D 128
#define K 16
#define STEPS 2
#define LAYERS 2
#define E_EDGES 8192
#define EDGE_BLOCKS 128

__device__ __forceinline__ float wave_reduce_sum(float v) {
    #pragma unroll
    for (int off = 32; off > 0; off >>= 1)
        v += __shfl_xor(v, off, 64);
    return v;
}

// Kernel A: Wsum[l][d] = sum_f layer_w[l][f][d]; also zero the output scalar.
__global__ void prep_kernel(const float* __restrict__ layer_w,
                            float* __restrict__ wsum,
                            float* __restrict__ out) {
    int t = threadIdx.x;            // 0..255
    int l = t >> 7, d = t & 127;
    float s = 0.f;
    const float* p = layer_w + (size_t)l * D * D + d;
    #pragma unroll 8
    for (int f = 0; f < D; ++f) s += p[(size_t)f * D];
    wsum[l * D + d] = s;
    if (t == 0) out[0] = 0.f;
}

// Kernel B: attention. One wave = 2 nodes.
// Phase 1: lane-per-neighbor (32 neighbors across both steps per node) —
//          full 128-dim dot in-lane, no shuffles, 32 independent gathers.
// Phase 2: softmax over 16-lane groups (4-level butterfly).
// Phase 3: dim-major aggregation (lane owns 4 dims), rows L1/L2-hot.
__global__ __launch_bounds__(256) void attn_kernel(
    const int* __restrict__ neighbors, const float* __restrict__ emb,
    const float* __restrict__ fc_w, const float* __restrict__ fc_b,
    float* __restrict__ att)
{
    __shared__ float wn_lds[D];
    const int t = threadIdx.x;
    if (t < D) wn_lds[t] = fc_w[t];          // w_n = fc_w[:D]
    __syncthreads();

    const int wave = (int)((blockIdx.x * blockDim.x + t) >> 6);
    const int lane = t & 63;
    const int half = lane >> 5;              // 0 -> node A, 1 -> node B
    const int sub  = lane & 31;
    const int node = 2 * wave + half;
    if (node >= N_NODES) return;             // grid sized exactly; safety only

    // ---- Phase 0: self score = dot(emb[node], w_s), dim-parallel in half ----
    const float4 e4  = *(const float4*)(emb + (size_t)node * D + sub * 4);
    const float4 ws4 = *(const float4*)(fc_w + D + sub * 4);
    float p = e4.x * ws4.x + e4.y * ws4.y + e4.z * ws4.z + e4.w * ws4.w;
    #pragma unroll
    for (int off = 16; off > 0; off >>= 1) p += __shfl_xor(p, off, 64);
    const float self_score = p;
    const float bias = fc_b[0];

    // ---- Phase 1: per-lane neighbor score (s = sub>>4, k = sub&15) ----
    const int s_step = sub >> 4;
    const int idx_l = neighbors[((size_t)s_step * N_NODES + node) * K + (sub & 15)];
    const float* vrow = emb + (size_t)idx_l * D;
    float dot = 0.f;
    #pragma unroll 8
    for (int j = 0; j < 32; ++j) {
        float4 v = *(const float4*)(vrow + j * 4);
        float4 w = *(const float4*)(wn_lds + j * 4);
        dot += v.x * w.x + v.y * w.y + v.z * w.z + v.w * w.w;
    }
    float raw = dot + self_score + bias;
    float sc = (raw >= 0.f) ? raw : 0.2f * raw;   // leaky relu

    // ---- Phase 2: softmax within each 16-lane (per-step) group ----
    float m = sc;
    #pragma unroll
    for (int off = 8; off > 0; off >>= 1) m = fmaxf(m, __shfl_xor(m, off, 64));
    float ex = __expf(sc - m);
    float den = ex;
    #pragma unroll
    for (int off = 8; off > 0; off >>= 1) den += __shfl_xor(den, off, 64);
    const float a = ex / den;

    // ---- Phase 3: dim-major aggregation; lane owns 4 dims of its node ----
    float4 acc;
    acc.x = (float)(STEPS * K) * e4.x;
    acc.y = (float)(STEPS * K) * e4.y;
    acc.z = (float)(STEPS * K) * e4.z;
    acc.w = (float)(STEPS * K) * e4.w;
    const int base_lane = half << 5;
    #pragma unroll 8
    for (int k = 0; k < 32; ++k) {
        int   sl   = base_lane + k;
        int   idxk = __shfl(idx_l, sl, 64);
        float ak   = __shfl(a, sl, 64);
        float4 v = *(const float4*)(emb + (size_t)idxk * D + sub * 4);
        acc.x += ak * v.x;
        acc.y += ak * v.y;
        acc.z += ak * v.z;
        acc.w += ak * v.w;
    }
    *(float4*)(att + (size_t)node * D + sub * 4) = acc;
}

// Kernel C: per-edge loss, grid-stride; one atomic per BLOCK (128 total).
__global__ __launch_bounds__(256) void edge_kernel(
    const int* __restrict__ edges, const int* __restrict__ labels,
    const float* __restrict__ emb, const float* __restrict__ att,
    const float* __restrict__ wsum, const float* __restrict__ layer_b,
    float* __restrict__ out)
{
    __shared__ float part[4];
    const int t = threadIdx.x;
    const int lane = t & 63, wv = t >> 6;
    const int gw = blockIdx.x * 4 + wv;          // global wave id
    const int d0 = lane * 2;

    const float2 w0 = *(const float2*)(wsum + d0);
    const float2 w1 = *(const float2*)(wsum + D + d0);
    const float2 b0 = *(const float2*)(layer_b + d0);
    const float2 b1 = *(const float2*)(layer_b + D + d0);

    float local = 0.f;
    for (int e = gw; e < E_EDGES; e += EDGE_BLOCKS * 4) {
        const int lab = labels[e];
        const int s = edges[2 * e], dnode = edges[2 * e + 1];
        const float* base = (lab == 1) ? att : emb;

        float2 xs = *(const float2*)(base + (size_t)s * D + d0);
        float2 xd = *(const float2*)(base + (size_t)dnode * D + d0);

        float ss0 = fmaxf(xs.x * w0.x + b0.x, 0.f) + fmaxf(xs.x * w1.x + b1.x, 0.f);
        float ss1 = fmaxf(xs.y * w0.y + b0.y, 0.f) + fmaxf(xs.y * w1.y + b1.y, 0.f);
        float dd0 = fmaxf(xd.x * w0.x + b0.x, 0.f) + fmaxf(xd.x * w1.x + b1.x, 0.f);
        float dd1 = fmaxf(xd.y * w0.y + b0.y, 0.f) + fmaxf(xd.y * w1.y + b1.y, 0.f);

        float t0 = ss0 - dd0, t1 = ss1 - dd1;
        float ssq = wave_reduce_sum(t0 * t0 + t1 * t1);   // broadcast to all lanes
        float diff = ssq * (1.0f / (float)D);
        float pred = __expf(-diff);
        float l = (float)lab - pred;
        local += 0.5f * l * l;                            // identical on all lanes
    }
    if (lane == 0) part[wv] = local;
    __syncthreads();
    if (t == 0) atomicAdd(out, part[0] + part[1] + part[2] + part[3]);
}

extern "C" void kernel_launch(void* const* d_in, const int* in_sizes, int n_in,
                              void* d_out, int out_size, void* d_ws, size_t ws_size,
                              hipStream_t stream) {
    const int*   edges     = (const int*)  d_in[0];
    const int*   labels    = (const int*)  d_in[1];
    const int*   neighbors = (const int*)  d_in[2];
    const float* emb       = (const float*)d_in[3];
    const float* fc_w      = (const float*)d_in[4];
    const float* fc_b      = (const float*)d_in[5];
    const float* layer_w   = (const float*)d_in[6];
    const float* layer_b   = (const float*)d_in[7];
    float* out  = (float*)d_out;
    float* att  = (float*)d_ws;                       // N*D floats = 10.24 MB
    float* wsum = att + (size_t)N_NODES * D;          // LAYERS*D floats

    prep_kernel<<<1, 256, 0, stream>>>(layer_w, wsum, out);

    // 2 nodes per wave, 4 waves per block -> 8 nodes/block
    int attn_blocks = (N_NODES / 2 + 3) / 4;          // 2500
    attn_kernel<<<attn_blocks, 256, 0, stream>>>(neighbors, emb, fc_w, fc_b, att);

    edge_kernel<<<EDGE_BLOCKS, 256, 0, stream>>>(edges, labels, emb, att, wsum, layer_b, out);
}

// Round 3
// 107.120 us; speedup vs baseline: 2.2043x; 1.4508x over previous
//
#include <hip/hip_runtime.h>

#define N_NODES 20000
#define D 128
#define K 16
#define STEPS 2
#define LAYERS 2
#define E_EDGES 8192

#define SCORE_BLOCKS 2500          // 8 nodes per block
#define FLAG_BLOCKS 32             // 8192 edges / 256
#define EDGE_BLOCKS 256            // 4 waves/block, 8 edges/wave

// ws layout (floats):
//   att    [N*D]      10.24 MB
//   wsum   [2*D]
//   nscore [N]
//   sscore [N]
//   flags  [N] (int)

// ---------------------------------------------------------------------------
// Pre-pass: one dispatch, three block-uniform jobs.
//   blocks [0, SCORE_BLOCKS)           : nscore/sscore for all nodes
//   blocks [SCORE_BLOCKS, +FLAG_BLOCKS): set flags for label-1 edge endpoints
//   last block                         : wsum[l][d] = sum_f layer_w[l][f][d]; out=0
// flags zeroed by prior memsetAsync.
// ---------------------------------------------------------------------------
__global__ __launch_bounds__(256) void pre_kernel(
    const int* __restrict__ edges, const int* __restrict__ labels,
    const float* __restrict__ emb, const float* __restrict__ fc_w,
    const float* __restrict__ layer_w,
    float* __restrict__ wsum, float* __restrict__ nscore,
    float* __restrict__ sscore, int* __restrict__ flags,
    float* __restrict__ out)
{
    const int b = blockIdx.x;
    const int t = threadIdx.x;

    if (b < SCORE_BLOCKS) {
        const int wave = (b * 256 + t) >> 6;
        const int lane = t & 63;
        const int half = lane >> 5, sub = lane & 31;
        const int node = 2 * wave + half;              // exact: 20000 total
        const float4 e4  = *(const float4*)(emb + (size_t)node * D + sub * 4);
        const float4 wn4 = *(const float4*)(fc_w + sub * 4);
        const float4 ws4 = *(const float4*)(fc_w + D + sub * 4);
        float dn = e4.x * wn4.x + e4.y * wn4.y + e4.z * wn4.z + e4.w * wn4.w;
        float ds = e4.x * ws4.x + e4.y * ws4.y + e4.z * ws4.z + e4.w * ws4.w;
        #pragma unroll
        for (int off = 16; off > 0; off >>= 1) {
            dn += __shfl_xor(dn, off, 64);
            ds += __shfl_xor(ds, off, 64);
        }
        if (sub == 0) { nscore[node] = dn; sscore[node] = ds; }
    } else if (b < SCORE_BLOCKS + FLAG_BLOCKS) {
        const int e = (b - SCORE_BLOCKS) * 256 + t;
        if (e < E_EDGES && labels[e] == 1) {
            flags[edges[2 * e]] = 1;
            flags[edges[2 * e + 1]] = 1;
        }
    } else {
        const int l = t >> 7, d = t & 127;
        const float* p = layer_w + (size_t)l * D * D + d;
        float s = 0.f;
        #pragma unroll
        for (int f = 0; f < D; f += 16) {
            float tmp[16];
            #pragma unroll
            for (int j = 0; j < 16; ++j) tmp[j] = p[(size_t)(f + j) * D];
            #pragma unroll
            for (int j = 0; j < 16; ++j) s += tmp[j];
        }
        wsum[t] = s;
        if (t == 0) out[0] = 0.f;
    }
}

// ---------------------------------------------------------------------------
// Attention: wave = 2 nodes. Score = nscore lookup (4B) instead of row gather;
// one gather pass for aggregation; unflagged nodes skipped entirely.
// ---------------------------------------------------------------------------
__global__ __launch_bounds__(256) void attn_kernel(
    const int* __restrict__ neighbors, const float* __restrict__ emb,
    const float* __restrict__ nscore, const float* __restrict__ sscore,
    const float* __restrict__ fc_b, const int* __restrict__ flags,
    float* __restrict__ att)
{
    const int wave = (int)((blockIdx.x * blockDim.x + threadIdx.x) >> 6);
    const int lane = threadIdx.x & 63;
    const int half = lane >> 5, sub = lane & 31;
    const int node = 2 * wave + half;                 // exact: 20000 total

    const int need = flags[node];
    if (__ballot(need != 0) == 0ULL) return;          // whole wave idle (~44%)

    if (need) {   // 32-lane-uniform; all shuffles below stay within the half
        const int step = sub >> 4;
        const int idx = neighbors[((size_t)step * N_NODES + node) * K + (sub & 15)];
        const float raw = nscore[idx] + sscore[node] + fc_b[0];
        float sc = (raw >= 0.f) ? raw : 0.2f * raw;   // leaky relu

        float m = sc;
        #pragma unroll
        for (int off = 8; off > 0; off >>= 1) m = fmaxf(m, __shfl_xor(m, off, 64));
        const float ex = __expf(sc - m);
        float den = ex;
        #pragma unroll
        for (int off = 8; off > 0; off >>= 1) den += __shfl_xor(den, off, 64);
        const float a = ex / den;

        const float4 e4 = *(const float4*)(emb + (size_t)node * D + sub * 4);
        float4 acc;
        acc.x = (float)(STEPS * K) * e4.x;
        acc.y = (float)(STEPS * K) * e4.y;
        acc.z = (float)(STEPS * K) * e4.z;
        acc.w = (float)(STEPS * K) * e4.w;
        const int base_lane = half << 5;
        #pragma unroll 8
        for (int k = 0; k < 32; ++k) {
            const int   sl   = base_lane + k;
            const int   idxk = __shfl(idx, sl, 64);
            const float ak   = __shfl(a, sl, 64);
            const float4 v = *(const float4*)(emb + (size_t)idxk * D + sub * 4);
            acc.x += ak * v.x;
            acc.y += ak * v.y;
            acc.z += ak * v.z;
            acc.w += ak * v.w;
        }
        *(float4*)(att + (size_t)node * D + sub * 4) = acc;
    }
}

// ---------------------------------------------------------------------------
// Edge loss: 1024 waves, 8 edges each, one atomic per block (256 total).
// ---------------------------------------------------------------------------
__global__ __launch_bounds__(256) void edge_kernel(
    const int* __restrict__ edges, const int* __restrict__ labels,
    const float* __restrict__ emb, const float* __restrict__ att,
    const float* __restrict__ wsum, const float* __restrict__ layer_b,
    float* __restrict__ out)
{
    __shared__ float part[4];
    const int t = threadIdx.x;
    const int lane = t & 63, wv = t >> 6;
    const int gw = blockIdx.x * 4 + wv;
    const int d0 = lane * 2;

    const float2 w0 = *(const float2*)(wsum + d0);
    const float2 w1 = *(const float2*)(wsum + D + d0);
    const float2 b0 = *(const float2*)(layer_b + d0);
    const float2 b1 = *(const float2*)(layer_b + D + d0);

    float local = 0.f;
    #pragma unroll 2
    for (int e = gw; e < E_EDGES; e += EDGE_BLOCKS * 4) {
        const int lab = labels[e];
        const int s = edges[2 * e], dnode = edges[2 * e + 1];
        const float* base = (lab == 1) ? att : emb;

        const float2 xs = *(const float2*)(base + (size_t)s * D + d0);
        const float2 xd = *(const float2*)(base + (size_t)dnode * D + d0);

        float ss0 = fmaxf(xs.x * w0.x + b0.x, 0.f) + fmaxf(xs.x * w1.x + b1.x, 0.f);
        float ss1 = fmaxf(xs.y * w0.y + b0.y, 0.f) + fmaxf(xs.y * w1.y + b1.y, 0.f);
        float dd0 = fmaxf(xd.x * w0.x + b0.x, 0.f) + fmaxf(xd.x * w1.x + b1.x, 0.f);
        float dd1 = fmaxf(xd.y * w0.y + b0.y, 0.f) + fmaxf(xd.y * w1.y + b1.y, 0.f);

        const float t0 = ss0 - dd0, t1 = ss1 - dd1;
        float v = t0 * t0 + t1 * t1;
        #pragma unroll
        for (int off = 32; off > 0; off >>= 1) v += __shfl_xor(v, off, 64);
        const float pred = __expf(-(v * (1.0f / (float)D)));
        const float l = (float)lab - pred;
        local += 0.5f * l * l;
    }
    if (lane == 0) part[wv] = local;
    __syncthreads();
    if (t == 0) atomicAdd(out, part[0] + part[1] + part[2] + part[3]);
}

extern "C" void kernel_launch(void* const* d_in, const int* in_sizes, int n_in,
                              void* d_out, int out_size, void* d_ws, size_t ws_size,
                              hipStream_t stream) {
    const int*   edges     = (const int*)  d_in[0];
    const int*   labels    = (const int*)  d_in[1];
    const int*   neighbors = (const int*)  d_in[2];
    const float* emb       = (const float*)d_in[3];
    const float* fc_w      = (const float*)d_in[4];
    const float* fc_b      = (const float*)d_in[5];
    const float* layer_w   = (const float*)d_in[6];
    const float* layer_b   = (const float*)d_in[7];
    float* out    = (float*)d_out;
    float* att    = (float*)d_ws;
    float* wsum   = att + (size_t)N_NODES * D;
    float* nscore = wsum + LAYERS * D;
    float* sscore = nscore + N_NODES;
    int*   flags  = (int*)(sscore + N_NODES);

    hipMemsetAsync(flags, 0, N_NODES * sizeof(int), stream);

    pre_kernel<<<SCORE_BLOCKS + FLAG_BLOCKS + 1, 256, 0, stream>>>(
        edges, labels, emb, fc_w, layer_w, wsum, nscore, sscore, flags, out);

    attn_kernel<<<SCORE_BLOCKS, 256, 0, stream>>>(
        neighbors, emb, nscore, sscore, fc_b, flags, att);

    edge_kernel<<<EDGE_BLOCKS, 256, 0, stream>>>(
        edges, labels, emb, att, wsum, layer_b, out);
}

// Round 4
// 94.860 us; speedup vs baseline: 2.4892x; 1.1292x over previous
//
#include <hip/hip_runtime.h>

#define N_NODES 20000
#define D 128
#define K 16
#define STEPS 2
#define E_EDGES 8192

#define SCORE_BLOCKS 2500          // 8 nodes per 256-thread block
#define EDGE_BLOCKS 256            // 512-thread blocks, 8 waves each
#define EDGE_WAVES (EDGE_BLOCKS * 8)

// ws layout (bytes):
//   emb_h  : ushort[N*D]   5.12 MB   bf16 shadow of embeddings
//   nscore : float[N]                emb[i] . w_n
//   sscore : float[N]                emb[i] . w_s
//   wsum   : float[2*D]              sum_f layer_w[l][f][d]

__device__ __forceinline__ unsigned short f2bf(float f) {
    unsigned u = __float_as_uint(f);
    u += 0x7FFFu + ((u >> 16) & 1u);       // round-to-nearest-even
    return (unsigned short)(u >> 16);
}
__device__ __forceinline__ float bf2f(unsigned short h) {
    return __uint_as_float(((unsigned)h) << 16);
}

// ---------------------------------------------------------------------------
// Pre-pass: blocks [0,SCORE_BLOCKS) compute nscore/sscore and the bf16 shadow
// (one coalesced stream over emb); last block computes wsum and zeroes out.
// ---------------------------------------------------------------------------
__global__ __launch_bounds__(256) void pre_kernel(
    const float* __restrict__ emb, const float* __restrict__ fc_w,
    const float* __restrict__ layer_w,
    unsigned short* __restrict__ emb_h, float* __restrict__ nscore,
    float* __restrict__ sscore, float* __restrict__ wsum,
    float* __restrict__ out)
{
    const int b = blockIdx.x;
    const int t = threadIdx.x;

    if (b < SCORE_BLOCKS) {
        const int wave = (b * 256 + t) >> 6;
        const int lane = t & 63;
        const int half = lane >> 5, sub = lane & 31;
        const int node = 2 * wave + half;              // exact: 20000 total

        const float4 e4  = *(const float4*)(emb + (size_t)node * D + sub * 4);
        const float4 wn4 = *(const float4*)(fc_w + sub * 4);
        const float4 ws4 = *(const float4*)(fc_w + D + sub * 4);
        float dn = e4.x * wn4.x + e4.y * wn4.y + e4.z * wn4.z + e4.w * wn4.w;
        float ds = e4.x * ws4.x + e4.y * ws4.y + e4.z * ws4.z + e4.w * ws4.w;
        #pragma unroll
        for (int off = 16; off > 0; off >>= 1) {
            dn += __shfl_xor(dn, off, 64);
            ds += __shfl_xor(ds, off, 64);
        }
        if (sub == 0) { nscore[node] = dn; sscore[node] = ds; }

        ushort4 h;
        h.x = f2bf(e4.x); h.y = f2bf(e4.y); h.z = f2bf(e4.z); h.w = f2bf(e4.w);
        *(ushort4*)(emb_h + (size_t)node * D + sub * 4) = h;
    } else {
        const int l = t >> 7, d = t & 127;
        const float* p = layer_w + (size_t)l * D * D + d;
        float s = 0.f;
        #pragma unroll
        for (int f = 0; f < D; f += 16) {
            float tmp[16];
            #pragma unroll
            for (int j = 0; j < 16; ++j) tmp[j] = p[(size_t)(f + j) * D];
            #pragma unroll
            for (int j = 0; j < 16; ++j) s += tmp[j];
        }
        wsum[t] = s;
        if (t == 0) out[0] = 0.f;
    }
}

// ---------------------------------------------------------------------------
// Fused edge kernel: one wave per edge slice. Lanes 0-31 own src, 32-63 own
// dst (4 dims each via sub*4). Label-1 edges compute attention inline:
//   score = nscore[nb] + sscore[node] + b  (fp32, precomputed dots)
//   softmax over 16-lane (step) groups, aggregation gathers bf16 rows.
// Then elementwise 2-layer relu-sum, shfl_xor(32) exchange, 32-lane reduce,
// exp loss; one atomic per block.
// ---------------------------------------------------------------------------
__global__ __launch_bounds__(512) void edge_kernel(
    const int* __restrict__ edges, const int* __restrict__ labels,
    const int* __restrict__ neighbors, const float* __restrict__ emb,
    const unsigned short* __restrict__ emb_h,
    const float* __restrict__ nscore, const float* __restrict__ sscore,
    const float* __restrict__ fc_b, const float* __restrict__ wsum,
    const float* __restrict__ layer_b, float* __restrict__ out)
{
    __shared__ float part[8];
    const int t = threadIdx.x;
    const int lane = t & 63, wv = t >> 6;
    const int half = lane >> 5, sub = lane & 31;
    const int gw = blockIdx.x * 8 + wv;               // 2048 waves
    const float bias = fc_b[0];

    // transform constants for my 4 dims
    const float4 w0 = *(const float4*)(wsum + sub * 4);
    const float4 w1 = *(const float4*)(wsum + D + sub * 4);
    const float4 b0 = *(const float4*)(layer_b + sub * 4);
    const float4 b1 = *(const float4*)(layer_b + D + sub * 4);

    float local = 0.f;
    for (int e = gw; e < E_EDGES; e += EDGE_WAVES) {  // 4 iterations
        const int lab = labels[e];                    // wave-uniform
        const int node = edges[2 * e + half];         // src for half0, dst for half1

        float4 x;
        if (lab == 1) {
            // ---- inline attention for `node` ----
            const int step = sub >> 4;
            const int idx = neighbors[((size_t)step * N_NODES + node) * K + (sub & 15)];
            const float raw = nscore[idx] + sscore[node] + bias;
            float sc = (raw >= 0.f) ? raw : 0.2f * raw;

            float m = sc;
            #pragma unroll
            for (int off = 8; off > 0; off >>= 1) m = fmaxf(m, __shfl_xor(m, off, 64));
            const float ex = __expf(sc - m);
            float den = ex;
            #pragma unroll
            for (int off = 8; off > 0; off >>= 1) den += __shfl_xor(den, off, 64);
            const float a = ex / den;

            const float4 e4 = *(const float4*)(emb + (size_t)node * D + sub * 4);
            x.x = (float)(STEPS * K) * e4.x;
            x.y = (float)(STEPS * K) * e4.y;
            x.z = (float)(STEPS * K) * e4.z;
            x.w = (float)(STEPS * K) * e4.w;
            const int base_lane = half << 5;
            #pragma unroll 8
            for (int k2 = 0; k2 < 32; ++k2) {
                const int   sl   = base_lane + k2;
                const int   idxk = __shfl(idx, sl, 64);
                const float ak   = __shfl(a, sl, 64);
                const ushort4 vh = *(const ushort4*)(emb_h + (size_t)idxk * D + sub * 4);
                x.x += ak * bf2f(vh.x);
                x.y += ak * bf2f(vh.y);
                x.z += ak * bf2f(vh.z);
                x.w += ak * bf2f(vh.w);
            }
        } else {
            x = *(const float4*)(emb + (size_t)node * D + sub * 4);
        }

        // ---- 2-layer elementwise transform, sum over layers ----
        float4 ss;
        ss.x = fmaxf(x.x * w0.x + b0.x, 0.f) + fmaxf(x.x * w1.x + b1.x, 0.f);
        ss.y = fmaxf(x.y * w0.y + b0.y, 0.f) + fmaxf(x.y * w1.y + b1.y, 0.f);
        ss.z = fmaxf(x.z * w0.z + b0.z, 0.f) + fmaxf(x.z * w1.z + b1.z, 0.f);
        ss.w = fmaxf(x.w * w0.w + b0.w, 0.f) + fmaxf(x.w * w1.w + b1.w, 0.f);

        // ---- exchange src<->dst halves, squared diff, reduce over 32 lanes ----
        const float ox = __shfl_xor(ss.x, 32, 64);
        const float oy = __shfl_xor(ss.y, 32, 64);
        const float oz = __shfl_xor(ss.z, 32, 64);
        const float ow = __shfl_xor(ss.w, 32, 64);
        const float dx = ss.x - ox, dy = ss.y - oy, dz = ss.z - oz, dw = ss.w - ow;
        float v = dx * dx + dy * dy + dz * dz + dw * dw;
        #pragma unroll
        for (int off = 16; off > 0; off >>= 1) v += __shfl_xor(v, off, 64);

        const float pred = __expf(-(v * (1.0f / (float)D)));
        const float l = (float)lab - pred;
        local += 0.5f * l * l;                         // identical on all lanes
    }
    if (lane == 0) part[wv] = local;
    __syncthreads();
    if (t == 0) {
        float s = 0.f;
        #pragma unroll
        for (int i = 0; i < 8; ++i) s += part[i];
        atomicAdd(out, s);
    }
}

extern "C" void kernel_launch(void* const* d_in, const int* in_sizes, int n_in,
                              void* d_out, int out_size, void* d_ws, size_t ws_size,
                              hipStream_t stream) {
    const int*   edges     = (const int*)  d_in[0];
    const int*   labels    = (const int*)  d_in[1];
    const int*   neighbors = (const int*)  d_in[2];
    const float* emb       = (const float*)d_in[3];
    const float* fc_w      = (const float*)d_in[4];
    const float* fc_b      = (const float*)d_in[5];
    const float* layer_w   = (const float*)d_in[6];
    const float* layer_b   = (const float*)d_in[7];
    float* out = (float*)d_out;

    unsigned short* emb_h = (unsigned short*)d_ws;
    float* nscore = (float*)((char*)d_ws + (size_t)N_NODES * D * 2);
    float* sscore = nscore + N_NODES;
    float* wsum   = sscore + N_NODES;

    pre_kernel<<<SCORE_BLOCKS + 1, 256, 0, stream>>>(
        emb, fc_w, layer_w, emb_h, nscore, sscore, wsum, out);

    edge_kernel<<<EDGE_BLOCKS, 512, 0, stream>>>(
        edges, labels, neighbors, emb, emb_h, nscore, sscore,
        fc_b, wsum, layer_b, out);
}